// Round 18
// baseline (344.301 us; speedup 1.0000x reference)
//
#include <hip/hip_runtime.h>

#define N_NODES 50000
#define M_PAD   50048   // padded rows so global_load_lds never reads past buffers
#define N_EDGES 800000
#define F_IN 64
#define HID 256
#define N_GRAPHS 128
#define N_OUT 24

typedef unsigned short ushort_t;
typedef __attribute__((ext_vector_type(8))) unsigned short us8;
typedef __attribute__((ext_vector_type(8))) __bf16 bf16x8;
typedef __attribute__((ext_vector_type(4))) float f32x4;

#define SLICE_US ((size_t)M_PAD * 32)  // ushorts per feature-slice (64B x M_PAD)

__device__ __forceinline__ unsigned short f2bf(float f) {
  unsigned u = __builtin_bit_cast(unsigned, f);
  return (unsigned short)((u + 0x7fffu + ((u >> 16) & 1u)) >> 16);
}
__device__ __forceinline__ float bf2f(unsigned short h) {
  return __builtin_bit_cast(float, (unsigned)h << 16);
}

__device__ __forceinline__ f32x4 mfma_bf16(us8 a, us8 b, f32x4 c) {
  return __builtin_amdgcn_mfma_f32_16x16x32_bf16(
      __builtin_bit_cast(bf16x8, a), __builtin_bit_cast(bf16x8, b), c, 0, 0, 0);
}

__device__ __forceinline__ void gload16(const ushort_t* g, ushort_t* l) {
  __builtin_amdgcn_global_load_lds(
      (const __attribute__((address_space(1))) void*)g,
      (__attribute__((address_space(3))) void*)l, 16, 0, 0);
}

// ---------------- CSR build (privatized histogram, atomic-free scatter) ----------------

__global__ void k_hist(const int* __restrict__ dst, int* __restrict__ deg_priv,
                       int* __restrict__ rank) {
  int e = blockIdx.x * 256 + threadIdx.x;
  if (e < N_EDGES) {
    int c = blockIdx.x & 7;
    rank[e] = atomicAdd(&deg_priv[c * N_NODES + dst[e]], 1);
  }
}

// batch is sorted: gofs[g] = first index with batch[i] >= g (binary search).
__global__ void k_gofs(const int* __restrict__ batch, int* __restrict__ gofs) {
  int t = threadIdx.x;
  if (t > N_GRAPHS) return;
  int lo = 0, hi = N_NODES;
  while (lo < hi) {
    int mid = (lo + hi) >> 1;
    if (batch[mid] < t) lo = mid + 1;
    else hi = mid;
  }
  gofs[t] = lo;
}

__global__ __launch_bounds__(1024) void k_scan1(int* __restrict__ deg_priv,
                                                int* __restrict__ deg,
                                                int* __restrict__ rowptr,
                                                int* __restrict__ partial) {
  __shared__ int s[1024];
  int t = threadIdx.x;
  int idx = blockIdx.x * 1024 + t;
  int v = 0;
  if (idx < N_NODES) {
    int run = 0;
#pragma unroll
    for (int c = 0; c < 8; ++c) {
      int dv = deg_priv[c * N_NODES + idx];
      deg_priv[c * N_NODES + idx] = run;  // exclusive offset among copies
      run += dv;
    }
    deg[idx] = run;
    v = run;
  }
  s[t] = v;
  __syncthreads();
  for (int off = 1; off < 1024; off <<= 1) {
    int a = (t >= off) ? s[t - off] : 0;
    __syncthreads();
    s[t] += a;
    __syncthreads();
  }
  if (idx < N_NODES) rowptr[idx] = s[t] - v;  // local exclusive
  if (t == 1023) partial[blockIdx.x] = s[1023];
}

__global__ void k_scan2(int* __restrict__ partial, int* __restrict__ rowptr) {
  __shared__ int s[64];
  int t = threadIdx.x;
  const int NB = (N_NODES + 1023) / 1024;
  int v = (t < NB) ? partial[t] : 0;
  s[t] = v;
  __syncthreads();
  for (int off = 1; off < 64; off <<= 1) {
    int a = (t >= off) ? s[t - off] : 0;
    __syncthreads();
    s[t] += a;
    __syncthreads();
  }
  if (t < NB) partial[t] = s[t] - v;
  if (t == NB - 1) rowptr[N_NODES] = s[t];
}

__global__ __launch_bounds__(1024) void k_scan3(const int* __restrict__ deg,
                                                const int* __restrict__ partial,
                                                int* __restrict__ rowptr,
                                                float* __restrict__ deg_inv) {
  int idx = blockIdx.x * 1024 + threadIdx.x;
  if (idx < N_NODES) {
    rowptr[idx] += partial[blockIdx.x];
    deg_inv[idx] = 1.0f / fmaxf((float)deg[idx], 1.0f);
  }
}

__global__ void k_place(const int* __restrict__ src, const int* __restrict__ dst,
                        const int* __restrict__ rowptr, const int* __restrict__ deg_priv,
                        const int* __restrict__ rank, int* __restrict__ esrc) {
  int e = blockIdx.x * 256 + threadIdx.x;
  if (e < N_EDGES) {
    int c = blockIdx.x & 7;
    int d = dst[e];
    esrc[rowptr[d] + deg_priv[c * N_NODES + d] + rank[e]] = src[e];
  }
}

// ---------------- degree counting sort (equal-degree waves in agg) ----------------

__global__ __launch_bounds__(1024) void k_dhist(const int* __restrict__ deg,
                                                int* __restrict__ blockhist) {
  __shared__ int h[64];
  int t = threadIdx.x;
  if (t < 64) h[t] = 0;
  __syncthreads();
  int idx = blockIdx.x * 1024 + t;
  if (idx < N_NODES) atomicAdd(&h[min(deg[idx], 63)], 1);
  __syncthreads();
  if (t < 64) blockhist[blockIdx.x * 64 + t] = h[t];
}

__global__ void k_dscan(const int* __restrict__ blockhist, int* __restrict__ blockbase) {
  __shared__ int tot[64];
  __shared__ int ofs[65];
  int t = threadIdx.x;  // 64 threads
  const int NB = (N_NODES + 1023) / 1024;
  int s = 0;
  for (int b = 0; b < NB; ++b) s += blockhist[b * 64 + t];
  tot[t] = s;
  __syncthreads();
  if (t == 0) {
    ofs[0] = 0;
    for (int i = 0; i < 64; ++i) ofs[i + 1] = ofs[i] + tot[i];
  }
  __syncthreads();
  int run = ofs[t];
  for (int b = 0; b < NB; ++b) {
    blockbase[b * 64 + t] = run;
    run += blockhist[b * 64 + t];
  }
}

__global__ __launch_bounds__(1024) void k_dplace(const int* __restrict__ deg,
                                                 const int* __restrict__ blockbase,
                                                 int* __restrict__ perm) {
  __shared__ int cur[64];
  int t = threadIdx.x;
  if (t < 64) cur[t] = blockbase[blockIdx.x * 64 + t];
  __syncthreads();
  int idx = blockIdx.x * 1024 + t;
  if (idx < N_NODES) {
    int bin = min(deg[idx], 63);
    int pos = atomicAdd(&cur[bin], 1);
    perm[pos] = idx;
  }
}

// ---------------- split/swizzle prep ----------------
// x: interleaved [hi 8 granules | lo 8 granules]; granule kb at slot kb^(row&7).

__global__ void k_prep_x(const float* __restrict__ x, ushort_t* __restrict__ xio) {
  int g = blockIdx.x * 256 + threadIdx.x;
  if (g >= N_NODES * 8) return;
  int row = g >> 3, kb = g & 7;
  const float* p = x + (size_t)row * F_IN + kb * 8;
  us8 H, L;
#pragma unroll
  for (int i = 0; i < 8; ++i) {
    float f = p[i];
    unsigned short hi = f2bf(f);
    H[i] = hi;
    L[i] = f2bf(f - bf2f(hi));
  }
  size_t ob = (size_t)row * 128 + (size_t)((kb ^ (row & 7)) << 3);
  *(us8*)&xio[ob] = H;
  *(us8*)&xio[ob + 64] = L;
}

// W in FRAGMENT-MAJOR layout for direct global->register MFMA B-operands:
// addr = ((nb2*qcs + qc)*2 + hl)*512 + lane*8, lane = fr + 16*kq,
// value = W[row = nb2*16+fr (nb2 includes side)][granule qc*4+kq], hl in {hi,lo}.
__global__ void k_prep_w(const float* __restrict__ w1lp, const float* __restrict__ w1rp,
                         const float* __restrict__ w2lp, const float* __restrict__ w2rp,
                         const float* __restrict__ w3lp, const float* __restrict__ w3rp,
                         ushort_t* __restrict__ wf1, ushort_t* __restrict__ wf2,
                         ushort_t* __restrict__ wf3) {
  int layer = blockIdx.z, side = blockIdx.y;
  const int Kg = (layer == 0) ? 8 : 32;
  const int qcs = Kg >> 2;
  int g = blockIdx.x * 256 + threadIdx.x;
  if (g >= 256 * Kg) return;
  const float* src = (layer == 0) ? (side ? w1rp : w1lp)
                   : (layer == 1) ? (side ? w2rp : w2lp)
                                  : (side ? w3rp : w3lp);
  ushort_t* dstf = (layer == 0) ? wf1 : (layer == 1) ? wf2 : wf3;
  int row = g / Kg, gb = g % Kg;
  const float* p = src + (size_t)row * (Kg * 8) + gb * 8;
  us8 H, L;
#pragma unroll
  for (int i = 0; i < 8; ++i) {
    float f = p[i];
    unsigned short hi = f2bf(f);
    H[i] = hi;
    L[i] = f2bf(f - bf2f(hi));
  }
  int nb2 = side * 16 + (row >> 4);
  int lane = (row & 15) + ((gb & 3) << 4);
  size_t base = ((size_t)(nb2 * qcs + (gb >> 2)) * 2) * 512 + lane * 8;
  *(us8*)&dstf[base] = H;
  *(us8*)&dstf[base + 512] = L;
}

// ---------------- aggregation (gather over CSR, degree-sorted) ----------------

// layer-1 agg: fp32 x gather, full wave per node (perm-indexed), 4-unroll.
__global__ __launch_bounds__(256) void k_agg64s(const float* __restrict__ x,
                                                const int* __restrict__ rowptr,
                                                const int* __restrict__ esrc,
                                                const float* __restrict__ deg_inv,
                                                const int* __restrict__ perm,
                                                ushort_t* __restrict__ oio) {
  int slot = blockIdx.x * 4 + (threadIdx.x >> 6);
  if (slot >= N_NODES) return;
  int node = perm[slot];
  int lane = threadIdx.x & 63;
  int e0 = rowptr[node], e1 = rowptr[node + 1];
  float acc = 0.f;
  int e = e0;
  for (; e + 4 <= e1; e += 4) {
    int s0 = esrc[e], s1 = esrc[e + 1], s2 = esrc[e + 2], s3 = esrc[e + 3];
    float v0 = x[(size_t)s0 * F_IN + lane];
    float v1 = x[(size_t)s1 * F_IN + lane];
    float v2 = x[(size_t)s2 * F_IN + lane];
    float v3 = x[(size_t)s3 * F_IN + lane];
    acc += v0 + v1 + v2 + v3;
  }
  for (; e < e1; ++e) acc += x[(size_t)esrc[e] * F_IN + lane];
  acc *= deg_inv[node];
  unsigned short hi = f2bf(acc);
  unsigned short lo = f2bf(acc - bf2f(hi));
  size_t rb = (size_t)node * 128;
  int slotk = ((lane >> 3) ^ (node & 7)) << 3;
  oio[rb + slotk + (lane & 7)] = hi;
  oio[rb + 64 + slotk + (lane & 7)] = lo;
}

// layers 2/3: h is SLICE-MAJOR (slice c = contiguous [M_PAD][4 granules], 64B rows;
// granule q of row r at slot q^(r&3)). Block b handles slice b&7 only (XCD-pure,
// 3.2MB L2-resident working set). ZERO-SHUFFLE: each 4-lane group owns one
// node-slice (perm-indexed -> equal-degree waves), lane q pinned to granule q.
__global__ __launch_bounds__(256) void k_agg256s(const ushort_t* __restrict__ hio,
                                                 const int* __restrict__ rowptr,
                                                 const int* __restrict__ esrc,
                                                 const float* __restrict__ deg_inv,
                                                 const int* __restrict__ perm,
                                                 ushort_t* __restrict__ oio) {
  int c = blockIdx.x & 7;
  const ushort_t* hs = hio + (size_t)c * SLICE_US;
  ushort_t* os = oio + (size_t)c * SLICE_US;
  int q = threadIdx.x & 3;
  int ns = threadIdx.x >> 2;  // node-slot 0..63
  for (int base = (blockIdx.x >> 3) * 64; base < N_NODES; base += 16384) {
    int slot = base + ns;
    if (slot >= N_NODES) continue;
    int node = perm[slot];
    int e0 = rowptr[node], e1 = rowptr[node + 1];
    float a[8] = {0.f, 0.f, 0.f, 0.f, 0.f, 0.f, 0.f, 0.f};
    int e = e0;
#pragma unroll 1
    for (; e + 4 <= e1; e += 4) {
      int s0 = esrc[e], s1 = esrc[e + 1], s2 = esrc[e + 2], s3 = esrc[e + 3];
      us8 v0 = *(const us8*)&hs[(size_t)s0 * 32 + ((q ^ (s0 & 3)) << 3)];
      us8 v1 = *(const us8*)&hs[(size_t)s1 * 32 + ((q ^ (s1 & 3)) << 3)];
      us8 v2 = *(const us8*)&hs[(size_t)s2 * 32 + ((q ^ (s2 & 3)) << 3)];
      us8 v3 = *(const us8*)&hs[(size_t)s3 * 32 + ((q ^ (s3 & 3)) << 3)];
#pragma unroll
      for (int i = 0; i < 8; ++i)
        a[i] += (bf2f(v0[i]) + bf2f(v1[i])) + (bf2f(v2[i]) + bf2f(v3[i]));
    }
    for (; e < e1; ++e) {
      int s = esrc[e];
      us8 v = *(const us8*)&hs[(size_t)s * 32 + ((q ^ (s & 3)) << 3)];
#pragma unroll
      for (int i = 0; i < 8; ++i) a[i] += bf2f(v[i]);
    }
    float di = deg_inv[node];
    us8 H;
#pragma unroll
    for (int i = 0; i < 8; ++i) H[i] = f2bf(a[i] * di);
    __builtin_nontemporal_store(
        H, (us8*)&os[(size_t)node * 32 + ((q ^ (node & 3)) << 3)]);
  }
}

// ---------------- split-bf16 MFMA GEMM (R16 + vectorized epilogue) ----------------
// out = relu(A1@W1^T + A2@W2^T + b). Tile 128x256, BK=64, 4 waves, grid 391;
// each wave owns ALL 128 rows x 64 cols. A: LDS double-buffered via
// global_load_lds, pre-swizzled source -> conflict-free fragment reads.
// W: fragment-major global->VGPR. SA=1: 3 terms. SA=0: 2 terms.
// EPILOGUE: per-wave 32-row chunks staged in LDS, re-read as 16B vectors,
// stored coalesced. mode 0: h slice-major bf16-hi. mode 1: fp32 row-major.

template <int SA>
__global__ __launch_bounds__(256, 2) void k_gemm_mfma(
    const ushort_t* __restrict__ A1, int k1g, const ushort_t* __restrict__ w1f,
    const ushort_t* __restrict__ A2, int k2g, const ushort_t* __restrict__ w2f,
    const float* __restrict__ bias, ushort_t* __restrict__ oio,
    float* __restrict__ ofp, int mode) {
  __shared__ __align__(16) ushort_t ldsA[2][SA ? 16384 : 8192];

  int t = threadIdx.x;
  int wv = t >> 6, lane = t & 63;
  int fr = lane & 15, kq = lane >> 4;
  int bm = blockIdx.x;
  int rowA0 = bm * 128;

  f32x4 acc[8][4];
#pragma unroll
  for (int m = 0; m < 8; ++m)
#pragma unroll
    for (int n = 0; n < 4; ++n) acc[m][n] = (f32x4)0.f;

  const int ns1 = k1g >> 3, ns2 = k2g >> 3, ns = ns1 + ns2;
  const int lj = lane & 7, lr8 = lane >> 3;

  auto stage = [&](int buf, int s) {
    bool p2 = s >= ns1;
    const ushort_t* A = p2 ? A2 : A1;
    int Kg = p2 ? k2g : k1g;
    int sl = p2 ? (s - ns1) : s;
#pragma unroll
    for (int i = 0; i < 4; ++i) {
      int row = wv * 32 + i * 8 + lr8;
      int R = rowA0 + row;
      int lo = (wv * 32 + i * 8) * 64;
      if (SA) {
        size_t offA = ((size_t)R * (Kg * 2) + sl * 8 + lj) * 8;
        gload16(A + offA, &ldsA[buf][lo]);
        gload16(A + offA + (size_t)Kg * 8, &ldsA[buf][8192 + lo]);
      } else {
        // pre-swizzled source: LDS position lj of row R gets logical granule
        // G = lj^(R&7); slice-major storage: slice sl*2+((lj>>2)^((R>>2)&1)),
        // slot lj&3 (agg's q^(r&3) swizzle cancels the low bits).
        size_t offA = (size_t)(sl * 2 + ((lj >> 2) ^ ((R >> 2) & 1))) * SLICE_US +
                      (size_t)R * 32 + (size_t)((lj & 3) << 3);
        gload16(A + offA, &ldsA[buf][lo]);
      }
    }
  };

  stage(0, 0);
  __syncthreads();
  int cur = 0;

  for (int s = 0; s < ns; ++s) {
    bool p2 = s >= ns1;
    const ushort_t* Wf = p2 ? w2f : w1f;
    int sl = p2 ? (s - ns1) : s;
    int qcs = (p2 ? k2g : k1g) >> 2;

    // W fragment loads for this step: issued FIRST (oldest in vmcnt order),
    // so waiting on them does not drain the A-stage issued below.
    us8 bh[2][4], bl[2][4];
#pragma unroll
    for (int kc = 0; kc < 2; ++kc)
#pragma unroll
      for (int n = 0; n < 4; ++n) {
        size_t base = ((size_t)((wv * 4 + n) * qcs + sl * 2 + kc) * 2) * 512 + lane * 8;
        bh[kc][n] = *(const us8*)&Wf[base];
        bl[kc][n] = *(const us8*)&Wf[base + 512];
      }

    if (s + 1 < ns) stage(cur ^ 1, s + 1);  // stays in flight through compute

#pragma unroll
    for (int kc = 0; kc < 2; ++kc) {
      int kg = kc * 4 + kq;
      int swk = (kg ^ (fr & 7)) << 3;  // full 8-slot swizzle, conflict-free
#pragma unroll
      for (int mh = 0; mh < 2; ++mh) {
        us8 ah[4], al[4];
#pragma unroll
        for (int m = 0; m < 4; ++m) {
          int off = ((mh * 64 + m * 16 + fr) << 6) + swk;
          ah[m] = *(const us8*)&ldsA[cur][off];
          if (SA) al[m] = *(const us8*)&ldsA[cur][8192 + off];
        }
        // term-major: 16 independent MFMAs per term
#pragma unroll
        for (int m = 0; m < 4; ++m)
#pragma unroll
          for (int n = 0; n < 4; ++n)
            acc[mh * 4 + m][n] = mfma_bf16(ah[m], bh[kc][n], acc[mh * 4 + m][n]);
#pragma unroll
        for (int m = 0; m < 4; ++m)
#pragma unroll
          for (int n = 0; n < 4; ++n)
            acc[mh * 4 + m][n] = mfma_bf16(ah[m], bl[kc][n], acc[mh * 4 + m][n]);
        if (SA) {
#pragma unroll
          for (int m = 0; m < 4; ++m)
#pragma unroll
            for (int n = 0; n < 4; ++n)
              acc[mh * 4 + m][n] = mfma_bf16(al[m], bh[kc][n], acc[mh * 4 + m][n]);
        }
      }
    }
    __syncthreads();  // drains next-step stage (issued one compute-phase ago)
    cur ^= 1;
  }

  // ---- vectorized epilogue (C/D map: col=lane&15, row=(lane>>4)*4+reg) ----
  float bv4[4];
#pragma unroll
  for (int n = 0; n < 4; ++n) bv4[n] = bias[wv * 64 + n * 16 + fr];

  if (mode == 0) {
    ushort_t* eb = &ldsA[0][0] + wv * 2048;  // per-wave 4KB chunk region
#pragma unroll
    for (int c = 0; c < 4; ++c) {
      __syncthreads();  // region reuse across chunks
#pragma unroll
      for (int mm = 0; mm < 2; ++mm) {
#pragma unroll
        for (int n = 0; n < 4; ++n) {
          f32x4 v = acc[c * 2 + mm][n];
#pragma unroll
          for (int r = 0; r < 4; ++r)
            eb[(mm * 16 + kq * 4 + r) * 64 + n * 16 + fr] =
                f2bf(fmaxf(v[r] + bv4[n], 0.f));
        }
      }
      __syncthreads();  // ds writes visible before vector re-read
#pragma unroll
      for (int j = 0; j < 4; ++j) {
        int rl = j * 8 + (lane >> 3);
        int g8 = lane & 7;
        us8 v = *(const us8*)&eb[rl * 64 + g8 * 8];
        int R = bm * 128 + c * 32 + rl;
        int gi = wv * 8 + g8;
        if (R < N_NODES) {
          size_t addr = (size_t)(gi >> 2) * SLICE_US + (size_t)R * 32 +
                        (size_t)(((gi & 3) ^ (R & 3)) << 3);
          *(us8*)&oio[addr] = v;
        }
      }
    }
  } else {
    float* ebf = (float*)&ldsA[0][0] + wv * 2048;  // per-wave 8KB region
#pragma unroll
    for (int c = 0; c < 4; ++c) {
      __syncthreads();
#pragma unroll
      for (int mm = 0; mm < 2; ++mm) {
#pragma unroll
        for (int n = 0; n < 4; ++n) {
          f32x4 v = acc[c * 2 + mm][n];
#pragma unroll
          for (int r = 0; r < 4; ++r)
            ebf[(mm * 16 + kq * 4 + r) * 64 + n * 16 + fr] =
                fmaxf(v[r] + bv4[n], 0.f);
        }
      }
      __syncthreads();
#pragma unroll
      for (int j = 0; j < 8; ++j) {
        int rl = j * 4 + (lane >> 4);
        int seg = lane & 15;
        f32x4 v = *(const f32x4*)&ebf[rl * 64 + seg * 4];
        int R = bm * 128 + c * 32 + rl;
        if (R < N_NODES)
          *(f32x4*)&ofp[(size_t)R * HID + wv * 64 + seg * 4] = v;
      }
    }
  }
}

// ---------------- global mean pool (parallel over graph x chunk) ----------------

__global__ __launch_bounds__(256) void k_pool(const float* __restrict__ h,
                                              const int* __restrict__ gofs,
                                              float* __restrict__ pooled) {
  int g = blockIdx.y, c = blockIdx.x;  // 16 chunks
  int r0 = gofs[g], r1 = gofs[g + 1];
  int rg = threadIdx.x >> 6, lane = threadIdx.x & 63;
  float ax = 0.f, ay = 0.f, az = 0.f, aw = 0.f;
  for (int r = r0 + c * 4 + rg; r < r1; r += 64) {
    float4 v = *(const float4*)&h[(size_t)r * HID + lane * 4];
    ax += v.x; ay += v.y; az += v.z; aw += v.w;
  }
  __shared__ float4 sm[4][64];
  sm[rg][lane] = make_float4(ax, ay, az, aw);
  __syncthreads();
  if (rg == 0) {
    float4 s0 = sm[0][lane], s1 = sm[1][lane], s2 = sm[2][lane], s3 = sm[3][lane];
    float* p = &pooled[g * HID + lane * 4];
    atomicAdd(p + 0, s0.x + s1.x + s2.x + s3.x);
    atomicAdd(p + 1, s0.y + s1.y + s2.y + s3.y);
    atomicAdd(p + 2, s0.z + s1.z + s2.z + s3.z);
    atomicAdd(p + 3, s0.w + s1.w + s2.w + s3.w);
  }
}

// ---------------- head ----------------

__global__ __launch_bounds__(128) void k_head(const float* __restrict__ pooled,
                                              const int* __restrict__ gofs,
                                              const float* __restrict__ w1,
                                              const float* __restrict__ b1,
                                              const float* __restrict__ w2,
                                              const float* __restrict__ b2,
                                              float* __restrict__ out) {
  __shared__ float p[HID];
  __shared__ float g1[HID / 2];
  int g = blockIdx.x, t = threadIdx.x;
  float inv = 1.f / fmaxf((float)(gofs[g + 1] - gofs[g]), 1.f);
  p[t] = pooled[g * HID + t] * inv;
  p[t + 128] = pooled[g * HID + 128 + t] * inv;
  __syncthreads();
  float s = b1[t];
#pragma unroll 4
  for (int k = 0; k < HID; ++k) s = fmaf(p[k], w1[t * HID + k], s);
  g1[t] = fmaxf(s, 0.f);
  __syncthreads();
  if (t < N_OUT) {
    float s2 = b2[t];
#pragma unroll 4
    for (int k = 0; k < HID / 2; ++k) s2 = fmaf(g1[k], w2[t * (HID / 2) + k], s2);
    out[g * N_OUT + t] = s2;
  }
}

// ---------------- launch ----------------

extern "C" void kernel_launch(void* const* d_in, const int* in_sizes, int n_in,
                              void* d_out, int out_size, void* d_ws, size_t ws_size,
                              hipStream_t stream) {
  const float* x      = (const float*)d_in[0];
  const int*   ei     = (const int*)d_in[1];
  const int*   batch  = (const int*)d_in[2];
  const float* w1lw   = (const float*)d_in[3];
  const float* b1     = (const float*)d_in[4];
  const float* w1rw   = (const float*)d_in[5];
  const float* w2lw   = (const float*)d_in[6];
  const float* b2     = (const float*)d_in[7];
  const float* w2rw   = (const float*)d_in[8];
  const float* w3lw   = (const float*)d_in[9];
  const float* b3     = (const float*)d_in[10];
  const float* w3rw   = (const float*)d_in[11];
  const float* lin1_w = (const float*)d_in[12];
  const float* lin1_b = (const float*)d_in[13];
  const float* lin2_w = (const float*)d_in[14];
  const float* lin2_b = (const float*)d_in[15];
  float* out = (float*)d_out;

  const int* srcIdx = ei;
  const int* dstIdx = ei + N_EDGES;

  size_t off = 0;
  auto carve = [&](size_t bytes) {
    size_t r = off;
    off += (bytes + 255) & ~(size_t)255;
    return r;
  };
  char* ws = (char*)d_ws;
  int*      deg_priv = (int*)(ws + carve((size_t)8 * N_NODES * 4));
  int*      deg      = (int*)(ws + carve((size_t)N_NODES * 4));
  int*      rank     = (int*)(ws + carve((size_t)N_EDGES * 4));
  int*      rowptr   = (int*)(ws + carve((size_t)(N_NODES + 1) * 4));
  float*    deg_inv  = (float*)(ws + carve((size_t)N_NODES * 4));
  int*      esrc     = (int*)(ws + carve((size_t)N_EDGES * 4));
  int*      partial  = (int*)(ws + carve(64 * 4));
  int*      gofs     = (int*)(ws + carve((N_GRAPHS + 1) * 4));
  int*      blockhist= (int*)(ws + carve((size_t)49 * 64 * 4));
  int*      blockbase= (int*)(ws + carve((size_t)49 * 64 * 4));
  int*      perm     = (int*)(ws + carve((size_t)N_NODES * 4));
  ushort_t* xio      = (ushort_t*)(ws + carve((size_t)M_PAD * 128 * 2));  // x split Kg=8
  ushort_t* agg1     = (ushort_t*)(ws + carve((size_t)M_PAD * 128 * 2));  // layer-1 agg split
  ushort_t* agg      = (ushort_t*)(ws + carve((size_t)M_PAD * 256 * 2));  // layers-2/3 agg, slice-major
  char*     h1blk    = ws + carve((size_t)M_PAD * HID * 4);  // h1 bf16-hi OR h3 fp32
  ushort_t* h1       = (ushort_t*)h1blk;
  float*    h3       = (float*)h1blk;  // alias: h1 dead before gemm3 writes
  ushort_t* h2       = (ushort_t*)(ws + carve((size_t)M_PAD * 256 * 2));
  ushort_t* wf1      = (ushort_t*)(ws + carve((size_t)2 * 32768 * 2));   // frag-major, Kg=8
  ushort_t* wf2      = (ushort_t*)(ws + carve((size_t)2 * 131072 * 2));  // frag-major, Kg=32
  ushort_t* wf3      = (ushort_t*)(ws + carve((size_t)2 * 131072 * 2));
  float*    pooled   = (float*)(ws + carve((size_t)N_GRAPHS * HID * 4));
  (void)ws_size; (void)n_in; (void)in_sizes; (void)out_size;

  hipMemsetAsync(deg_priv, 0, (size_t)8 * N_NODES * 4, stream);
  hipMemsetAsync(pooled, 0, (size_t)N_GRAPHS * HID * 4, stream);

  const int EB = (N_EDGES + 255) / 256;
  const int SB = (N_NODES + 1023) / 1024;

  k_hist<<<EB, 256, 0, stream>>>(dstIdx, deg_priv, rank);
  k_gofs<<<1, 256, 0, stream>>>(batch, gofs);
  k_scan1<<<SB, 1024, 0, stream>>>(deg_priv, deg, rowptr, partial);
  k_scan2<<<1, 64, 0, stream>>>(partial, rowptr);
  k_scan3<<<SB, 1024, 0, stream>>>(deg, partial, rowptr, deg_inv);
  k_place<<<EB, 256, 0, stream>>>(srcIdx, dstIdx, rowptr, deg_priv, rank, esrc);

  // degree counting sort -> perm (equal-degree waves in agg kernels)
  k_dhist<<<SB, 1024, 0, stream>>>(deg, blockhist);
  k_dscan<<<1, 64, 0, stream>>>(blockhist, blockbase);
  k_dplace<<<SB, 1024, 0, stream>>>(deg, blockbase, perm);

  k_prep_x<<<(N_NODES * 8 + 255) / 256, 256, 0, stream>>>(x, xio);
  k_prep_w<<<dim3(32, 2, 3), 256, 0, stream>>>(w1lw, w1rw, w2lw, w2rw, w3lw, w3rw,
                                               wf1, wf2, wf3);

  const int GB = (N_NODES + 127) / 128;  // 391, 1-D grid (128-row, full-N tiles)
  const int AB = N_NODES / 4;            // layer-1 agg grid
  const int AGB = 2048;                  // slice-pure agg grid (b&7 = slice -> XCD)

  // layer 1 (3-term split A)
  k_agg64s<<<AB, 256, 0, stream>>>(x, rowptr, esrc, deg_inv, perm, agg1);
  k_gemm_mfma<1><<<GB, 256, 0, stream>>>(agg1, 8, wf1,
                                         xio, 8, wf1 + 32768,
                                         b1, h1, nullptr, 0);
  // layer 2 (A hi-only, 2-term)
  k_agg256s<<<AGB, 256, 0, stream>>>(h1, rowptr, esrc, deg_inv, perm, agg);
  k_gemm_mfma<0><<<GB, 256, 0, stream>>>(agg, 32, wf2,
                                         h1, 32, wf2 + 131072,
                                         b2, h2, nullptr, 0);
  // layer 3 (fp32 out for pooling; h3 aliases dead h1)
  k_agg256s<<<AGB, 256, 0, stream>>>(h2, rowptr, esrc, deg_inv, perm, agg);
  k_gemm_mfma<0><<<GB, 256, 0, stream>>>(agg, 32, wf3,
                                         h2, 32, wf3 + 131072,
                                         b3, nullptr, h3, 1);

  k_pool<<<dim3(16, N_GRAPHS), 256, 0, stream>>>(h3, gofs, pooled);
  k_head<<<N_GRAPHS, 128, 0, stream>>>(pooled, gofs, lin1_w, lin1_b, lin2_w, lin2_b, out);
}

// Round 19
// 325.213 us; speedup vs baseline: 1.0587x; 1.0587x over previous
//
#include <hip/hip_runtime.h>

#define N_NODES 50000
#define M_PAD   50048   // padded rows so global_load_lds never reads past buffers
#define N_EDGES 800000
#define F_IN 64
#define HID 256
#define N_GRAPHS 128
#define N_OUT 24

typedef unsigned short ushort_t;
typedef __attribute__((ext_vector_type(8))) unsigned short us8;
typedef __attribute__((ext_vector_type(8))) __bf16 bf16x8;
typedef __attribute__((ext_vector_type(4))) float f32x4;

#define SLICE_US ((size_t)M_PAD * 32)  // ushorts per feature-slice (64B x M_PAD)

__device__ __forceinline__ unsigned short f2bf(float f) {
  unsigned u = __builtin_bit_cast(unsigned, f);
  return (unsigned short)((u + 0x7fffu + ((u >> 16) & 1u)) >> 16);
}
__device__ __forceinline__ float bf2f(unsigned short h) {
  return __builtin_bit_cast(float, (unsigned)h << 16);
}

__device__ __forceinline__ f32x4 mfma_bf16(us8 a, us8 b, f32x4 c) {
  return __builtin_amdgcn_mfma_f32_16x16x32_bf16(
      __builtin_bit_cast(bf16x8, a), __builtin_bit_cast(bf16x8, b), c, 0, 0, 0);
}

__device__ __forceinline__ void gload16(const ushort_t* g, ushort_t* l) {
  __builtin_amdgcn_global_load_lds(
      (const __attribute__((address_space(1))) void*)g,
      (__attribute__((address_space(3))) void*)l, 16, 0, 0);
}

// ---------------- CSR build (privatized histogram, DEGREE-SORTED layout) ----------------

__global__ void k_hist(const int* __restrict__ dst, int* __restrict__ deg_priv,
                       int* __restrict__ rank) {
  int e = blockIdx.x * 256 + threadIdx.x;
  if (e < N_EDGES) {
    int c = blockIdx.x & 7;
    rank[e] = atomicAdd(&deg_priv[c * N_NODES + dst[e]], 1);
  }
}

// batch is sorted: gofs[g] = first index with batch[i] >= g (binary search).
__global__ void k_gofs(const int* __restrict__ batch, int* __restrict__ gofs) {
  int t = threadIdx.x;
  if (t > N_GRAPHS) return;
  int lo = 0, hi = N_NODES;
  while (lo < hi) {
    int mid = (lo + hi) >> 1;
    if (batch[mid] < t) lo = mid + 1;
    else hi = mid;
  }
  gofs[t] = lo;
}

// reduce 8 privatized copies -> per-copy exclusive offsets (in place), deg, deg_inv.
__global__ __launch_bounds__(1024) void k_degsum(int* __restrict__ deg_priv,
                                                 int* __restrict__ deg,
                                                 float* __restrict__ deg_inv) {
  int idx = blockIdx.x * 1024 + threadIdx.x;
  if (idx < N_NODES) {
    int run = 0;
#pragma unroll
    for (int c = 0; c < 8; ++c) {
      int dv = deg_priv[c * N_NODES + idx];
      deg_priv[c * N_NODES + idx] = run;
      run += dv;
    }
    deg[idx] = run;
    deg_inv[idx] = 1.0f / fmaxf((float)run, 1.0f);
  }
}

// ---- degree counting sort: perm (sorted slot -> node) + sortpos (node -> slot) ----

__global__ __launch_bounds__(1024) void k_dhist(const int* __restrict__ deg,
                                                int* __restrict__ blockhist) {
  __shared__ int h[64];
  int t = threadIdx.x;
  if (t < 64) h[t] = 0;
  __syncthreads();
  int idx = blockIdx.x * 1024 + t;
  if (idx < N_NODES) atomicAdd(&h[min(deg[idx], 63)], 1);
  __syncthreads();
  if (t < 64) blockhist[blockIdx.x * 64 + t] = h[t];
}

__global__ void k_dscan(const int* __restrict__ blockhist, int* __restrict__ blockbase) {
  __shared__ int tot[64];
  __shared__ int ofs[65];
  int t = threadIdx.x;  // 64 threads
  const int NB = (N_NODES + 1023) / 1024;
  int s = 0;
  for (int b = 0; b < NB; ++b) s += blockhist[b * 64 + t];
  tot[t] = s;
  __syncthreads();
  if (t == 0) {
    ofs[0] = 0;
    for (int i = 0; i < 64; ++i) ofs[i + 1] = ofs[i] + tot[i];
  }
  __syncthreads();
  int run = ofs[t];
  for (int b = 0; b < NB; ++b) {
    blockbase[b * 64 + t] = run;
    run += blockhist[b * 64 + t];
  }
}

__global__ __launch_bounds__(1024) void k_dplace(const int* __restrict__ deg,
                                                 const int* __restrict__ blockbase,
                                                 int* __restrict__ perm,
                                                 int* __restrict__ sortpos) {
  __shared__ int cur[64];
  int t = threadIdx.x;
  if (t < 64) cur[t] = blockbase[blockIdx.x * 64 + t];
  __syncthreads();
  int idx = blockIdx.x * 1024 + t;
  if (idx < N_NODES) {
    int bin = min(deg[idx], 63);
    int pos = atomicAdd(&cur[bin], 1);
    perm[pos] = idx;
    sortpos[idx] = pos;
  }
}

// ---- scan of sorted degrees -> srowptr (edge base per sorted slot) ----

__global__ __launch_bounds__(1024) void k_sscan1(const int* __restrict__ deg,
                                                 const int* __restrict__ perm,
                                                 int* __restrict__ srowptr,
                                                 int* __restrict__ partial) {
  __shared__ int s[1024];
  int t = threadIdx.x;
  int idx = blockIdx.x * 1024 + t;
  int v = (idx < N_NODES) ? deg[perm[idx]] : 0;
  s[t] = v;
  __syncthreads();
  for (int off = 1; off < 1024; off <<= 1) {
    int a = (t >= off) ? s[t - off] : 0;
    __syncthreads();
    s[t] += a;
    __syncthreads();
  }
  if (idx < N_NODES) srowptr[idx] = s[t] - v;  // local exclusive
  if (t == 1023) partial[blockIdx.x] = s[1023];
}

__global__ void k_sscan2(int* __restrict__ partial, int* __restrict__ srowptr) {
  __shared__ int s[64];
  int t = threadIdx.x;
  const int NB = (N_NODES + 1023) / 1024;
  int v = (t < NB) ? partial[t] : 0;
  s[t] = v;
  __syncthreads();
  for (int off = 1; off < 64; off <<= 1) {
    int a = (t >= off) ? s[t - off] : 0;
    __syncthreads();
    s[t] += a;
    __syncthreads();
  }
  if (t < NB) partial[t] = s[t] - v;
  if (t == NB - 1) srowptr[N_NODES] = s[t];
}

__global__ __launch_bounds__(1024) void k_sscan3(const int* __restrict__ partial,
                                                 int* __restrict__ srowptr) {
  int idx = blockIdx.x * 1024 + threadIdx.x;
  if (idx < N_NODES) srowptr[idx] += partial[blockIdx.x];
}

// atomic-free placement into sorted-CSR: slot = srowptr[sortpos[d]] + copyoff + rank.
__global__ void k_place(const int* __restrict__ src, const int* __restrict__ dst,
                        const int* __restrict__ srowptr, const int* __restrict__ sortpos,
                        const int* __restrict__ deg_priv, const int* __restrict__ rank,
                        int* __restrict__ esrc) {
  int e = blockIdx.x * 256 + threadIdx.x;
  if (e < N_EDGES) {
    int c = blockIdx.x & 7;
    int d = dst[e];
    esrc[srowptr[sortpos[d]] + deg_priv[c * N_NODES + d] + rank[e]] = src[e];
  }
}

// ---------------- split/swizzle prep ----------------
// x: interleaved [hi 8 granules | lo 8 granules]; granule kb at slot kb^(row&7).

__global__ void k_prep_x(const float* __restrict__ x, ushort_t* __restrict__ xio) {
  int g = blockIdx.x * 256 + threadIdx.x;
  if (g >= N_NODES * 8) return;
  int row = g >> 3, kb = g & 7;
  const float* p = x + (size_t)row * F_IN + kb * 8;
  us8 H, L;
#pragma unroll
  for (int i = 0; i < 8; ++i) {
    float f = p[i];
    unsigned short hi = f2bf(f);
    H[i] = hi;
    L[i] = f2bf(f - bf2f(hi));
  }
  size_t ob = (size_t)row * 128 + (size_t)((kb ^ (row & 7)) << 3);
  *(us8*)&xio[ob] = H;
  *(us8*)&xio[ob + 64] = L;
}

// W in FRAGMENT-MAJOR layout for direct global->register MFMA B-operands.
__global__ void k_prep_w(const float* __restrict__ w1lp, const float* __restrict__ w1rp,
                         const float* __restrict__ w2lp, const float* __restrict__ w2rp,
                         const float* __restrict__ w3lp, const float* __restrict__ w3rp,
                         ushort_t* __restrict__ wf1, ushort_t* __restrict__ wf2,
                         ushort_t* __restrict__ wf3) {
  int layer = blockIdx.z, side = blockIdx.y;
  const int Kg = (layer == 0) ? 8 : 32;
  const int qcs = Kg >> 2;
  int g = blockIdx.x * 256 + threadIdx.x;
  if (g >= 256 * Kg) return;
  const float* src = (layer == 0) ? (side ? w1rp : w1lp)
                   : (layer == 1) ? (side ? w2rp : w2lp)
                                  : (side ? w3rp : w3lp);
  ushort_t* dstf = (layer == 0) ? wf1 : (layer == 1) ? wf2 : wf3;
  int row = g / Kg, gb = g % Kg;
  const float* p = src + (size_t)row * (Kg * 8) + gb * 8;
  us8 H, L;
#pragma unroll
  for (int i = 0; i < 8; ++i) {
    float f = p[i];
    unsigned short hi = f2bf(f);
    H[i] = hi;
    L[i] = f2bf(f - bf2f(hi));
  }
  int nb2 = side * 16 + (row >> 4);
  int lane = (row & 15) + ((gb & 3) << 4);
  size_t base = ((size_t)(nb2 * qcs + (gb >> 2)) * 2) * 512 + lane * 8;
  *(us8*)&dstf[base] = H;
  *(us8*)&dstf[base + 512] = L;
}

// ---------------- aggregation (gather over sorted CSR) ----------------

// layer-1 agg: fp32 x gather, full wave per sorted slot, 4-unroll.
// esrc sequential (sorted CSR), node = perm[slot] for deg_inv + output.
__global__ __launch_bounds__(256) void k_agg64s(const float* __restrict__ x,
                                                const int* __restrict__ srowptr,
                                                const int* __restrict__ esrc,
                                                const float* __restrict__ deg_inv,
                                                const int* __restrict__ perm,
                                                ushort_t* __restrict__ oio) {
  int slot = blockIdx.x * 4 + (threadIdx.x >> 6);
  if (slot >= N_NODES) return;
  int node = perm[slot];
  int lane = threadIdx.x & 63;
  int e0 = srowptr[slot], e1 = srowptr[slot + 1];
  float acc = 0.f;
  int e = e0;
  for (; e + 4 <= e1; e += 4) {
    int s0 = esrc[e], s1 = esrc[e + 1], s2 = esrc[e + 2], s3 = esrc[e + 3];
    float v0 = x[(size_t)s0 * F_IN + lane];
    float v1 = x[(size_t)s1 * F_IN + lane];
    float v2 = x[(size_t)s2 * F_IN + lane];
    float v3 = x[(size_t)s3 * F_IN + lane];
    acc += v0 + v1 + v2 + v3;
  }
  for (; e < e1; ++e) acc += x[(size_t)esrc[e] * F_IN + lane];
  acc *= deg_inv[node];
  unsigned short hi = f2bf(acc);
  unsigned short lo = f2bf(acc - bf2f(hi));
  size_t rb = (size_t)node * 128;
  int slotk = ((lane >> 3) ^ (node & 7)) << 3;
  oio[rb + slotk + (lane & 7)] = hi;
  oio[rb + 64 + slotk + (lane & 7)] = lo;
}

// layers 2/3: h is SLICE-MAJOR (slice c = contiguous [M_PAD][4 granules], 64B rows;
// granule q of row r at slot q^(r&3)). Block b handles slice b&7 only (XCD-pure,
// 3.2MB L2-resident). ZERO-SHUFFLE: each 4-lane group owns one sorted node-slot
// (equal-degree waves, sequential esrc), lane q pinned to granule q.
__global__ __launch_bounds__(256) void k_agg256s(const ushort_t* __restrict__ hio,
                                                 const int* __restrict__ srowptr,
                                                 const int* __restrict__ esrc,
                                                 const float* __restrict__ deg_inv,
                                                 const int* __restrict__ perm,
                                                 ushort_t* __restrict__ oio) {
  int c = blockIdx.x & 7;
  const ushort_t* hs = hio + (size_t)c * SLICE_US;
  ushort_t* os = oio + (size_t)c * SLICE_US;
  int q = threadIdx.x & 3;
  int ns = threadIdx.x >> 2;  // node-slot 0..63
  for (int base = (blockIdx.x >> 3) * 64; base < N_NODES; base += 16384) {
    int slot = base + ns;
    if (slot >= N_NODES) continue;
    int node = perm[slot];
    int e0 = srowptr[slot], e1 = srowptr[slot + 1];
    float a[8] = {0.f, 0.f, 0.f, 0.f, 0.f, 0.f, 0.f, 0.f};
    int e = e0;
#pragma unroll 1
    for (; e + 4 <= e1; e += 4) {
      int s0 = esrc[e], s1 = esrc[e + 1], s2 = esrc[e + 2], s3 = esrc[e + 3];
      us8 v0 = *(const us8*)&hs[(size_t)s0 * 32 + ((q ^ (s0 & 3)) << 3)];
      us8 v1 = *(const us8*)&hs[(size_t)s1 * 32 + ((q ^ (s1 & 3)) << 3)];
      us8 v2 = *(const us8*)&hs[(size_t)s2 * 32 + ((q ^ (s2 & 3)) << 3)];
      us8 v3 = *(const us8*)&hs[(size_t)s3 * 32 + ((q ^ (s3 & 3)) << 3)];
#pragma unroll
      for (int i = 0; i < 8; ++i)
        a[i] += (bf2f(v0[i]) + bf2f(v1[i])) + (bf2f(v2[i]) + bf2f(v3[i]));
    }
    for (; e < e1; ++e) {
      int s = esrc[e];
      us8 v = *(const us8*)&hs[(size_t)s * 32 + ((q ^ (s & 3)) << 3)];
#pragma unroll
      for (int i = 0; i < 8; ++i) a[i] += bf2f(v[i]);
    }
    float di = deg_inv[node];
    us8 H;
#pragma unroll
    for (int i = 0; i < 8; ++i) H[i] = f2bf(a[i] * di);
    __builtin_nontemporal_store(
        H, (us8*)&os[(size_t)node * 32 + ((q ^ (node & 3)) << 3)]);
  }
}

// ---------------- split-bf16 MFMA GEMM (R17: 2-phase pipelined + vec epilogue) ----
// out = relu(A1@W1^T + A2@W2^T + b). Tile 128x256, BK=64, 4 waves, grid 391;
// each wave owns ALL 128 rows x 64 cols. A: LDS double-buffered via
// global_load_lds, pre-swizzled source -> conflict-free fragment reads.
// W: fragment-major global->VGPR. SA=1: 3 terms. SA=0: 2 terms.
// EPILOGUE: per-wave 32-row chunks staged in LDS, re-read as 16B vectors,
// stored coalesced. mode 0: h slice-major bf16-hi. mode 1: fp32 row-major.

template <int SA>
__global__ __launch_bounds__(256, 2) void k_gemm_mfma(
    const ushort_t* __restrict__ A1, int k1g, const ushort_t* __restrict__ w1f,
    const ushort_t* __restrict__ A2, int k2g, const ushort_t* __restrict__ w2f,
    const float* __restrict__ bias, ushort_t* __restrict__ oio,
    float* __restrict__ ofp, int mode) {
  __shared__ __align__(16) ushort_t ldsA[2][SA ? 16384 : 8192];

  int t = threadIdx.x;
  int wv = t >> 6, lane = t & 63;
  int fr = lane & 15, kq = lane >> 4;
  int bm = blockIdx.x;
  int rowA0 = bm * 128;

  f32x4 acc[8][4];
#pragma unroll
  for (int m = 0; m < 8; ++m)
#pragma unroll
    for (int n = 0; n < 4; ++n) acc[m][n] = (f32x4)0.f;

  const int ns1 = k1g >> 3, ns2 = k2g >> 3, ns = ns1 + ns2;
  const int lj = lane & 7, lr8 = lane >> 3;

  auto stage = [&](int buf, int s) {
    bool p2 = s >= ns1;
    const ushort_t* A = p2 ? A2 : A1;
    int Kg = p2 ? k2g : k1g;
    int sl = p2 ? (s - ns1) : s;
#pragma unroll
    for (int i = 0; i < 4; ++i) {
      int row = wv * 32 + i * 8 + lr8;
      int R = rowA0 + row;
      int lo = (wv * 32 + i * 8) * 64;
      if (SA) {
        size_t offA = ((size_t)R * (Kg * 2) + sl * 8 + lj) * 8;
        gload16(A + offA, &ldsA[buf][lo]);
        gload16(A + offA + (size_t)Kg * 8, &ldsA[buf][8192 + lo]);
      } else {
        // pre-swizzled source: LDS position lj of row R gets logical granule
        // G = lj^(R&7); slice-major storage: slice sl*2+((lj>>2)^((R>>2)&1)),
        // slot lj&3 (agg's q^(r&3) swizzle cancels the low bits).
        size_t offA = (size_t)(sl * 2 + ((lj >> 2) ^ ((R >> 2) & 1))) * SLICE_US +
                      (size_t)R * 32 + (size_t)((lj & 3) << 3);
        gload16(A + offA, &ldsA[buf][lo]);
      }
    }
  };

  stage(0, 0);
  __syncthreads();
  int cur = 0;

  for (int s = 0; s < ns; ++s) {
    bool p2 = s >= ns1;
    const ushort_t* Wf = p2 ? w2f : w1f;
    int sl = p2 ? (s - ns1) : s;
    int qcs = (p2 ? k2g : k1g) >> 2;

    // W fragment loads for this step: issued FIRST (oldest in vmcnt order),
    // so waiting on them does not drain the A-stage issued below.
    us8 bh[2][4], bl[2][4];
#pragma unroll
    for (int kc = 0; kc < 2; ++kc)
#pragma unroll
      for (int n = 0; n < 4; ++n) {
        size_t base = ((size_t)((wv * 4 + n) * qcs + sl * 2 + kc) * 2) * 512 + lane * 8;
        bh[kc][n] = *(const us8*)&Wf[base];
        bl[kc][n] = *(const us8*)&Wf[base + 512];
      }

    if (s + 1 < ns) stage(cur ^ 1, s + 1);  // stays in flight through compute

#pragma unroll
    for (int kc = 0; kc < 2; ++kc) {
      int kg = kc * 4 + kq;
      int swk = (kg ^ (fr & 7)) << 3;  // full 8-slot swizzle, conflict-free
#pragma unroll
      for (int mh = 0; mh < 2; ++mh) {
        us8 ah[4], al[4];
#pragma unroll
        for (int m = 0; m < 4; ++m) {
          int off = ((mh * 64 + m * 16 + fr) << 6) + swk;
          ah[m] = *(const us8*)&ldsA[cur][off];
          if (SA) al[m] = *(const us8*)&ldsA[cur][8192 + off];
        }
        // term-major: 16 independent MFMAs per term
#pragma unroll
        for (int m = 0; m < 4; ++m)
#pragma unroll
          for (int n = 0; n < 4; ++n)
            acc[mh * 4 + m][n] = mfma_bf16(ah[m], bh[kc][n], acc[mh * 4 + m][n]);
#pragma unroll
        for (int m = 0; m < 4; ++m)
#pragma unroll
          for (int n = 0; n < 4; ++n)
            acc[mh * 4 + m][n] = mfma_bf16(ah[m], bl[kc][n], acc[mh * 4 + m][n]);
        if (SA) {
#pragma unroll
          for (int m = 0; m < 4; ++m)
#pragma unroll
            for (int n = 0; n < 4; ++n)
              acc[mh * 4 + m][n] = mfma_bf16(al[m], bh[kc][n], acc[mh * 4 + m][n]);
        }
      }
    }
    __syncthreads();  // drains next-step stage (issued one compute-phase ago)
    cur ^= 1;
  }

  // ---- vectorized epilogue (C/D map: col=lane&15, row=(lane>>4)*4+reg) ----
  float bv4[4];
#pragma unroll
  for (int n = 0; n < 4; ++n) bv4[n] = bias[wv * 64 + n * 16 + fr];

  if (mode == 0) {
    ushort_t* eb = &ldsA[0][0] + wv * 2048;  // per-wave 4KB chunk region
#pragma unroll
    for (int c = 0; c < 4; ++c) {
      __syncthreads();  // region reuse across chunks
#pragma unroll
      for (int mm = 0; mm < 2; ++mm) {
#pragma unroll
        for (int n = 0; n < 4; ++n) {
          f32x4 v = acc[c * 2 + mm][n];
#pragma unroll
          for (int r = 0; r < 4; ++r)
            eb[(mm * 16 + kq * 4 + r) * 64 + n * 16 + fr] =
                f2bf(fmaxf(v[r] + bv4[n], 0.f));
        }
      }
      __syncthreads();  // ds writes visible before vector re-read
#pragma unroll
      for (int j = 0; j < 4; ++j) {
        int rl = j * 8 + (lane >> 3);
        int g8 = lane & 7;
        us8 v = *(const us8*)&eb[rl * 64 + g8 * 8];
        int R = bm * 128 + c * 32 + rl;
        int gi = wv * 8 + g8;
        if (R < N_NODES) {
          size_t addr = (size_t)(gi >> 2) * SLICE_US + (size_t)R * 32 +
                        (size_t)(((gi & 3) ^ (R & 3)) << 3);
          *(us8*)&oio[addr] = v;
        }
      }
    }
  } else {
    float* ebf = (float*)&ldsA[0][0] + wv * 2048;  // per-wave 8KB region
#pragma unroll
    for (int c = 0; c < 4; ++c) {
      __syncthreads();
#pragma unroll
      for (int mm = 0; mm < 2; ++mm) {
#pragma unroll
        for (int n = 0; n < 4; ++n) {
          f32x4 v = acc[c * 2 + mm][n];
#pragma unroll
          for (int r = 0; r < 4; ++r)
            ebf[(mm * 16 + kq * 4 + r) * 64 + n * 16 + fr] =
                fmaxf(v[r] + bv4[n], 0.f);
        }
      }
      __syncthreads();
#pragma unroll
      for (int j = 0; j < 8; ++j) {
        int rl = j * 4 + (lane >> 4);
        int seg = lane & 15;
        f32x4 v = *(const f32x4*)&ebf[rl * 64 + seg * 4];
        int R = bm * 128 + c * 32 + rl;
        if (R < N_NODES)
          *(f32x4*)&ofp[(size_t)R * HID + wv * 64 + seg * 4] = v;
      }
    }
  }
}

// ---------------- global mean pool (parallel over graph x chunk) ----------------

__global__ __launch_bounds__(256) void k_pool(const float* __restrict__ h,
                                              const int* __restrict__ gofs,
                                              float* __restrict__ pooled) {
  int g = blockIdx.y, c = blockIdx.x;  // 16 chunks
  int r0 = gofs[g], r1 = gofs[g + 1];
  int rg = threadIdx.x >> 6, lane = threadIdx.x & 63;
  float ax = 0.f, ay = 0.f, az = 0.f, aw = 0.f;
  for (int r = r0 + c * 4 + rg; r < r1; r += 64) {
    float4 v = *(const float4*)&h[(size_t)r * HID + lane * 4];
    ax += v.x; ay += v.y; az += v.z; aw += v.w;
  }
  __shared__ float4 sm[4][64];
  sm[rg][lane] = make_float4(ax, ay, az, aw);
  __syncthreads();
  if (rg == 0) {
    float4 s0 = sm[0][lane], s1 = sm[1][lane], s2 = sm[2][lane], s3 = sm[3][lane];
    float* p = &pooled[g * HID + lane * 4];
    atomicAdd(p + 0, s0.x + s1.x + s2.x + s3.x);
    atomicAdd(p + 1, s0.y + s1.y + s2.y + s3.y);
    atomicAdd(p + 2, s0.z + s1.z + s2.z + s3.z);
    atomicAdd(p + 3, s0.w + s1.w + s2.w + s3.w);
  }
}

// ---------------- head ----------------

__global__ __launch_bounds__(128) void k_head(const float* __restrict__ pooled,
                                              const int* __restrict__ gofs,
                                              const float* __restrict__ w1,
                                              const float* __restrict__ b1,
                                              const float* __restrict__ w2,
                                              const float* __restrict__ b2,
                                              float* __restrict__ out) {
  __shared__ float p[HID];
  __shared__ float g1[HID / 2];
  int g = blockIdx.x, t = threadIdx.x;
  float inv = 1.f / fmaxf((float)(gofs[g + 1] - gofs[g]), 1.f);
  p[t] = pooled[g * HID + t] * inv;
  p[t + 128] = pooled[g * HID + 128 + t] * inv;
  __syncthreads();
  float s = b1[t];
#pragma unroll 4
  for (int k = 0; k < HID; ++k) s = fmaf(p[k], w1[t * HID + k], s);
  g1[t] = fmaxf(s, 0.f);
  __syncthreads();
  if (t < N_OUT) {
    float s2 = b2[t];
#pragma unroll 4
    for (int k = 0; k < HID / 2; ++k) s2 = fmaf(g1[k], w2[t * (HID / 2) + k], s2);
    out[g * N_OUT + t] = s2;
  }
}

// ---------------- launch ----------------

extern "C" void kernel_launch(void* const* d_in, const int* in_sizes, int n_in,
                              void* d_out, int out_size, void* d_ws, size_t ws_size,
                              hipStream_t stream) {
  const float* x      = (const float*)d_in[0];
  const int*   ei     = (const int*)d_in[1];
  const int*   batch  = (const int*)d_in[2];
  const float* w1lw   = (const float*)d_in[3];
  const float* b1     = (const float*)d_in[4];
  const float* w1rw   = (const float*)d_in[5];
  const float* w2lw   = (const float*)d_in[6];
  const float* b2     = (const float*)d_in[7];
  const float* w2rw   = (const float*)d_in[8];
  const float* w3lw   = (const float*)d_in[9];
  const float* b3     = (const float*)d_in[10];
  const float* w3rw   = (const float*)d_in[11];
  const float* lin1_w = (const float*)d_in[12];
  const float* lin1_b = (const float*)d_in[13];
  const float* lin2_w = (const float*)d_in[14];
  const float* lin2_b = (const float*)d_in[15];
  float* out = (float*)d_out;

  const int* srcIdx = ei;
  const int* dstIdx = ei + N_EDGES;

  size_t off = 0;
  auto carve = [&](size_t bytes) {
    size_t r = off;
    off += (bytes + 255) & ~(size_t)255;
    return r;
  };
  char* ws = (char*)d_ws;
  int*      deg_priv = (int*)(ws + carve((size_t)8 * N_NODES * 4));
  int*      deg      = (int*)(ws + carve((size_t)N_NODES * 4));
  int*      rank     = (int*)(ws + carve((size_t)N_EDGES * 4));
  int*      srowptr  = (int*)(ws + carve((size_t)(N_NODES + 1) * 4));
  float*    deg_inv  = (float*)(ws + carve((size_t)N_NODES * 4));
  int*      esrc     = (int*)(ws + carve((size_t)N_EDGES * 4));
  int*      partial  = (int*)(ws + carve(64 * 4));
  int*      gofs     = (int*)(ws + carve((N_GRAPHS + 1) * 4));
  int*      blockhist= (int*)(ws + carve((size_t)49 * 64 * 4));
  int*      blockbase= (int*)(ws + carve((size_t)49 * 64 * 4));
  int*      perm     = (int*)(ws + carve((size_t)N_NODES * 4));
  int*      sortpos  = (int*)(ws + carve((size_t)N_NODES * 4));
  ushort_t* xio      = (ushort_t*)(ws + carve((size_t)M_PAD * 128 * 2));  // x split Kg=8
  ushort_t* agg1     = (ushort_t*)(ws + carve((size_t)M_PAD * 128 * 2));  // layer-1 agg split
  ushort_t* agg      = (ushort_t*)(ws + carve((size_t)M_PAD * 256 * 2));  // layers-2/3 agg, slice-major
  char*     h1blk    = ws + carve((size_t)M_PAD * HID * 4);  // h1 bf16-hi OR h3 fp32
  ushort_t* h1       = (ushort_t*)h1blk;
  float*    h3       = (float*)h1blk;  // alias: h1 dead before gemm3 writes
  ushort_t* h2       = (ushort_t*)(ws + carve((size_t)M_PAD * 256 * 2));
  ushort_t* wf1      = (ushort_t*)(ws + carve((size_t)2 * 32768 * 2));   // frag-major, Kg=8
  ushort_t* wf2      = (ushort_t*)(ws + carve((size_t)2 * 131072 * 2));  // frag-major, Kg=32
  ushort_t* wf3      = (ushort_t*)(ws + carve((size_t)2 * 131072 * 2));
  float*    pooled   = (float*)(ws + carve((size_t)N_GRAPHS * HID * 4));
  (void)ws_size; (void)n_in; (void)in_sizes; (void)out_size;

  hipMemsetAsync(deg_priv, 0, (size_t)8 * N_NODES * 4, stream);
  hipMemsetAsync(pooled, 0, (size_t)N_GRAPHS * HID * 4, stream);

  const int EB = (N_EDGES + 255) / 256;
  const int SB = (N_NODES + 1023) / 1024;

  k_hist<<<EB, 256, 0, stream>>>(dstIdx, deg_priv, rank);
  k_gofs<<<1, 256, 0, stream>>>(batch, gofs);
  k_degsum<<<SB, 1024, 0, stream>>>(deg_priv, deg, deg_inv);
  // degree counting sort -> perm/sortpos
  k_dhist<<<SB, 1024, 0, stream>>>(deg, blockhist);
  k_dscan<<<1, 64, 0, stream>>>(blockhist, blockbase);
  k_dplace<<<SB, 1024, 0, stream>>>(deg, blockbase, perm, sortpos);
  // sorted-CSR rowptr
  k_sscan1<<<SB, 1024, 0, stream>>>(deg, perm, srowptr, partial);
  k_sscan2<<<1, 64, 0, stream>>>(partial, srowptr);
  k_sscan3<<<SB, 1024, 0, stream>>>(partial, srowptr);
  k_place<<<EB, 256, 0, stream>>>(srcIdx, dstIdx, srowptr, sortpos, deg_priv, rank, esrc);

  k_prep_x<<<(N_NODES * 8 + 255) / 256, 256, 0, stream>>>(x, xio);
  k_prep_w<<<dim3(32, 2, 3), 256, 0, stream>>>(w1lw, w1rw, w2lw, w2rw, w3lw, w3rw,
                                               wf1, wf2, wf3);

  const int GB = (N_NODES + 127) / 128;  // 391, 1-D grid (128-row, full-N tiles)
  const int AB = (N_NODES + 3) / 4;      // layer-1 agg grid
  const int AGB = 2048;                  // slice-pure agg grid (b&7 = slice -> XCD)

  // layer 1 (3-term split A)
  k_agg64s<<<AB, 256, 0, stream>>>(x, srowptr, esrc, deg_inv, perm, agg1);
  k_gemm_mfma<1><<<GB, 256, 0, stream>>>(agg1, 8, wf1,
                                         xio, 8, wf1 + 32768,
                                         b1, h1, nullptr, 0);
  // layer 2 (A hi-only, 2-term)
  k_agg256s<<<AGB, 256, 0, stream>>>(h1, srowptr, esrc, deg_inv, perm, agg);
  k_gemm_mfma<0><<<GB, 256, 0, stream>>>(agg, 32, wf2,
                                         h1, 32, wf2 + 131072,
                                         b2, h2, nullptr, 0);
  // layer 3 (fp32 out for pooling; h3 aliases dead h1)
  k_agg256s<<<AGB, 256, 0, stream>>>(h2, srowptr, esrc, deg_inv, perm, agg);
  k_gemm_mfma<0><<<GB, 256, 0, stream>>>(agg, 32, wf3,
                                         h2, 32, wf3 + 131072,
                                         b3, nullptr, h3, 1);

  k_pool<<<dim3(16, N_GRAPHS), 256, 0, stream>>>(h3, gofs, pooled);
  k_head<<<N_GRAPHS, 128, 0, stream>>>(pooled, gofs, lin1_w, lin1_b, lin2_w, lin2_b, out);
}

// Round 20
// 307.919 us; speedup vs baseline: 1.1182x; 1.0562x over previous
//
#include <hip/hip_runtime.h>

#define N_NODES 50000
#define M_PAD   50048   // padded rows so global_load_lds never reads past buffers
#define N_EDGES 800000
#define F_IN 64
#define HID 256
#define N_GRAPHS 128
#define N_OUT 24

typedef unsigned short ushort_t;
typedef __attribute__((ext_vector_type(8))) unsigned short us8;
typedef __attribute__((ext_vector_type(8))) __bf16 bf16x8;
typedef __attribute__((ext_vector_type(4))) float f32x4;

#define SLICE_US ((size_t)M_PAD * 32)  // ushorts per feature-slice (64B x M_PAD)

__device__ __forceinline__ unsigned short f2bf(float f) {
  unsigned u = __builtin_bit_cast(unsigned, f);
  return (unsigned short)((u + 0x7fffu + ((u >> 16) & 1u)) >> 16);
}
__device__ __forceinline__ float bf2f(unsigned short h) {
  return __builtin_bit_cast(float, (unsigned)h << 16);
}

__device__ __forceinline__ f32x4 mfma_bf16(us8 a, us8 b, f32x4 c) {
  return __builtin_amdgcn_mfma_f32_16x16x32_bf16(
      __builtin_bit_cast(bf16x8, a), __builtin_bit_cast(bf16x8, b), c, 0, 0, 0);
}

__device__ __forceinline__ void gload16(const ushort_t* g, ushort_t* l) {
  __builtin_amdgcn_global_load_lds(
      (const __attribute__((address_space(1))) void*)g,
      (__attribute__((address_space(3))) void*)l, 16, 0, 0);
}

// ---------------- CSR build (privatized histogram, atomic-free scatter) ----------------

__global__ void k_hist(const int* __restrict__ dst, int* __restrict__ deg_priv,
                       int* __restrict__ rank) {
  int e = blockIdx.x * 256 + threadIdx.x;
  if (e < N_EDGES) {
    int c = blockIdx.x & 7;
    rank[e] = atomicAdd(&deg_priv[c * N_NODES + dst[e]], 1);
  }
}

// batch is sorted: gofs[g] = first index with batch[i] >= g (binary search).
__global__ void k_gofs(const int* __restrict__ batch, int* __restrict__ gofs) {
  int t = threadIdx.x;
  if (t > N_GRAPHS) return;
  int lo = 0, hi = N_NODES;
  while (lo < hi) {
    int mid = (lo + hi) >> 1;
    if (batch[mid] < t) lo = mid + 1;
    else hi = mid;
  }
  gofs[t] = lo;
}

__global__ __launch_bounds__(1024) void k_scan1(int* __restrict__ deg_priv,
                                                int* __restrict__ deg,
                                                int* __restrict__ rowptr,
                                                int* __restrict__ partial) {
  __shared__ int s[1024];
  int t = threadIdx.x;
  int idx = blockIdx.x * 1024 + t;
  int v = 0;
  if (idx < N_NODES) {
    int run = 0;
#pragma unroll
    for (int c = 0; c < 8; ++c) {
      int dv = deg_priv[c * N_NODES + idx];
      deg_priv[c * N_NODES + idx] = run;  // exclusive offset among copies
      run += dv;
    }
    deg[idx] = run;
    v = run;
  }
  s[t] = v;
  __syncthreads();
  for (int off = 1; off < 1024; off <<= 1) {
    int a = (t >= off) ? s[t - off] : 0;
    __syncthreads();
    s[t] += a;
    __syncthreads();
  }
  if (idx < N_NODES) rowptr[idx] = s[t] - v;  // local exclusive
  if (t == 1023) partial[blockIdx.x] = s[1023];
}

__global__ void k_scan2(int* __restrict__ partial, int* __restrict__ rowptr) {
  __shared__ int s[64];
  int t = threadIdx.x;
  const int NB = (N_NODES + 1023) / 1024;
  int v = (t < NB) ? partial[t] : 0;
  s[t] = v;
  __syncthreads();
  for (int off = 1; off < 64; off <<= 1) {
    int a = (t >= off) ? s[t - off] : 0;
    __syncthreads();
    s[t] += a;
    __syncthreads();
  }
  if (t < NB) partial[t] = s[t] - v;
  if (t == NB - 1) rowptr[N_NODES] = s[t];
}

__global__ __launch_bounds__(1024) void k_scan3(const int* __restrict__ deg,
                                                const int* __restrict__ partial,
                                                int* __restrict__ rowptr,
                                                float* __restrict__ deg_inv) {
  int idx = blockIdx.x * 1024 + threadIdx.x;
  if (idx < N_NODES) {
    rowptr[idx] += partial[blockIdx.x];
    deg_inv[idx] = 1.0f / fmaxf((float)deg[idx], 1.0f);
  }
}

__global__ void k_place(const int* __restrict__ src, const int* __restrict__ dst,
                        const int* __restrict__ rowptr, const int* __restrict__ deg_priv,
                        const int* __restrict__ rank, int* __restrict__ esrc) {
  int e = blockIdx.x * 256 + threadIdx.x;
  if (e < N_EDGES) {
    int c = blockIdx.x & 7;
    int d = dst[e];
    esrc[rowptr[d] + deg_priv[c * N_NODES + d] + rank[e]] = src[e];
  }
}

// ---------------- split/swizzle prep ----------------
// x: interleaved [hi 8 granules | lo 8 granules]; granule kb at slot kb^(row&7).

__global__ void k_prep_x(const float* __restrict__ x, ushort_t* __restrict__ xio) {
  int g = blockIdx.x * 256 + threadIdx.x;
  if (g >= N_NODES * 8) return;
  int row = g >> 3, kb = g & 7;
  const float* p = x + (size_t)row * F_IN + kb * 8;
  us8 H, L;
#pragma unroll
  for (int i = 0; i < 8; ++i) {
    float f = p[i];
    unsigned short hi = f2bf(f);
    H[i] = hi;
    L[i] = f2bf(f - bf2f(hi));
  }
  size_t ob = (size_t)row * 128 + (size_t)((kb ^ (row & 7)) << 3);
  *(us8*)&xio[ob] = H;
  *(us8*)&xio[ob + 64] = L;
}

// W in FRAGMENT-MAJOR layout for direct global->register MFMA B-operands.
__global__ void k_prep_w(const float* __restrict__ w1lp, const float* __restrict__ w1rp,
                         const float* __restrict__ w2lp, const float* __restrict__ w2rp,
                         const float* __restrict__ w3lp, const float* __restrict__ w3rp,
                         ushort_t* __restrict__ wf1, ushort_t* __restrict__ wf2,
                         ushort_t* __restrict__ wf3) {
  int layer = blockIdx.z, side = blockIdx.y;
  const int Kg = (layer == 0) ? 8 : 32;
  const int qcs = Kg >> 2;
  int g = blockIdx.x * 256 + threadIdx.x;
  if (g >= 256 * Kg) return;
  const float* src = (layer == 0) ? (side ? w1rp : w1lp)
                   : (layer == 1) ? (side ? w2rp : w2lp)
                                  : (side ? w3rp : w3lp);
  ushort_t* dstf = (layer == 0) ? wf1 : (layer == 1) ? wf2 : wf3;
  int row = g / Kg, gb = g % Kg;
  const float* p = src + (size_t)row * (Kg * 8) + gb * 8;
  us8 H, L;
#pragma unroll
  for (int i = 0; i < 8; ++i) {
    float f = p[i];
    unsigned short hi = f2bf(f);
    H[i] = hi;
    L[i] = f2bf(f - bf2f(hi));
  }
  int nb2 = side * 16 + (row >> 4);
  int lane = (row & 15) + ((gb & 3) << 4);
  size_t base = ((size_t)(nb2 * qcs + (gb >> 2)) * 2) * 512 + lane * 8;
  *(us8*)&dstf[base] = H;
  *(us8*)&dstf[base + 512] = L;
}

// ---------------- aggregation (gather over CSR, 8-deep MLP) ----------------

// layer-1 agg: fp32 x gather, full wave per node, 8-deep batched loads.
__global__ __launch_bounds__(256) void k_agg64s(const float* __restrict__ x,
                                                const int* __restrict__ rowptr,
                                                const int* __restrict__ esrc,
                                                const float* __restrict__ deg_inv,
                                                ushort_t* __restrict__ oio) {
  int node = blockIdx.x * 4 + (threadIdx.x >> 6);
  if (node >= N_NODES) return;
  int lane = threadIdx.x & 63;
  int e0 = rowptr[node], e1 = rowptr[node + 1];
  float acc = 0.f;
  int e = e0;
#pragma unroll 1
  for (; e + 8 <= e1; e += 8) {
    int sidx[8];
#pragma unroll
    for (int j = 0; j < 8; ++j) sidx[j] = esrc[e + j];
    float v[8];
#pragma unroll
    for (int j = 0; j < 8; ++j) v[j] = x[(size_t)sidx[j] * F_IN + lane];
    acc += ((v[0] + v[1]) + (v[2] + v[3])) + ((v[4] + v[5]) + (v[6] + v[7]));
  }
  if (e + 4 <= e1) {
    int s0 = esrc[e], s1 = esrc[e + 1], s2 = esrc[e + 2], s3 = esrc[e + 3];
    float v0 = x[(size_t)s0 * F_IN + lane];
    float v1 = x[(size_t)s1 * F_IN + lane];
    float v2 = x[(size_t)s2 * F_IN + lane];
    float v3 = x[(size_t)s3 * F_IN + lane];
    acc += (v0 + v1) + (v2 + v3);
    e += 4;
  }
  for (; e < e1; ++e) acc += x[(size_t)esrc[e] * F_IN + lane];
  acc *= deg_inv[node];
  unsigned short hi = f2bf(acc);
  unsigned short lo = f2bf(acc - bf2f(hi));
  size_t rb = (size_t)node * 128;
  int slot = ((lane >> 3) ^ (node & 7)) << 3;
  oio[rb + slot + (lane & 7)] = hi;
  oio[rb + 64 + slot + (lane & 7)] = lo;
}

// layers 2/3: h is SLICE-MAJOR (slice c = contiguous [M_PAD][4 granules], 64B rows;
// granule q of row r at slot q^(r&3)). Block b handles slice b&7 only (XCD-pure,
// 3.2MB L2-resident working set). ZERO-SHUFFLE: each 4-lane group owns one node-
// slice, lane q pinned to granule q; 8-deep batched loads hide L2 latency.
__global__ __launch_bounds__(256) void k_agg256s(const ushort_t* __restrict__ hio,
                                                 const int* __restrict__ rowptr,
                                                 const int* __restrict__ esrc,
                                                 const float* __restrict__ deg_inv,
                                                 ushort_t* __restrict__ oio) {
  int c = blockIdx.x & 7;
  const ushort_t* hs = hio + (size_t)c * SLICE_US;
  ushort_t* os = oio + (size_t)c * SLICE_US;
  int q = threadIdx.x & 3;
  int ns = threadIdx.x >> 2;  // node-slot 0..63
  for (int base = (blockIdx.x >> 3) * 64; base < N_NODES; base += 16384) {
    int node = base + ns;
    if (node >= N_NODES) continue;
    int e0 = rowptr[node], e1 = rowptr[node + 1];
    float a[8] = {0.f, 0.f, 0.f, 0.f, 0.f, 0.f, 0.f, 0.f};
    int e = e0;
#pragma unroll 1
    for (; e + 8 <= e1; e += 8) {
      int sidx[8];
#pragma unroll
      for (int j = 0; j < 8; ++j) sidx[j] = esrc[e + j];
      us8 v[8];
#pragma unroll
      for (int j = 0; j < 8; ++j)
        v[j] = *(const us8*)&hs[(size_t)sidx[j] * 32 + ((q ^ (sidx[j] & 3)) << 3)];
#pragma unroll
      for (int j = 0; j < 8; ++j)
#pragma unroll
        for (int i = 0; i < 8; ++i) a[i] += bf2f(v[j][i]);
    }
    if (e + 4 <= e1) {
      int s0 = esrc[e], s1 = esrc[e + 1], s2 = esrc[e + 2], s3 = esrc[e + 3];
      us8 v0 = *(const us8*)&hs[(size_t)s0 * 32 + ((q ^ (s0 & 3)) << 3)];
      us8 v1 = *(const us8*)&hs[(size_t)s1 * 32 + ((q ^ (s1 & 3)) << 3)];
      us8 v2 = *(const us8*)&hs[(size_t)s2 * 32 + ((q ^ (s2 & 3)) << 3)];
      us8 v3 = *(const us8*)&hs[(size_t)s3 * 32 + ((q ^ (s3 & 3)) << 3)];
#pragma unroll
      for (int i = 0; i < 8; ++i)
        a[i] += (bf2f(v0[i]) + bf2f(v1[i])) + (bf2f(v2[i]) + bf2f(v3[i]));
      e += 4;
    }
    for (; e < e1; ++e) {
      int s = esrc[e];
      us8 v = *(const us8*)&hs[(size_t)s * 32 + ((q ^ (s & 3)) << 3)];
#pragma unroll
      for (int i = 0; i < 8; ++i) a[i] += bf2f(v[i]);
    }
    float di = deg_inv[node];
    us8 H;
#pragma unroll
    for (int i = 0; i < 8; ++i) H[i] = f2bf(a[i] * di);
    __builtin_nontemporal_store(
        H, (us8*)&os[(size_t)node * 32 + ((q ^ (node & 3)) << 3)]);
  }
}

// ---------------- split-bf16 MFMA GEMM (R17: 2-phase pipelined + vec epilogue) ----
// out = relu(A1@W1^T + A2@W2^T + b). Tile 128x256, BK=64, 4 waves, grid 391;
// each wave owns ALL 128 rows x 64 cols. A: LDS double-buffered via
// global_load_lds, pre-swizzled source -> conflict-free fragment reads.
// W: fragment-major global->VGPR. SA=1: 3 terms. SA=0: 2 terms.
// EPILOGUE: per-wave 32-row chunks staged in LDS, re-read as 16B vectors,
// stored coalesced. mode 0: h slice-major bf16-hi. mode 1: fp32 row-major.

template <int SA>
__global__ __launch_bounds__(256, 2) void k_gemm_mfma(
    const ushort_t* __restrict__ A1, int k1g, const ushort_t* __restrict__ w1f,
    const ushort_t* __restrict__ A2, int k2g, const ushort_t* __restrict__ w2f,
    const float* __restrict__ bias, ushort_t* __restrict__ oio,
    float* __restrict__ ofp, int mode) {
  __shared__ __align__(16) ushort_t ldsA[2][SA ? 16384 : 8192];

  int t = threadIdx.x;
  int wv = t >> 6, lane = t & 63;
  int fr = lane & 15, kq = lane >> 4;
  int bm = blockIdx.x;
  int rowA0 = bm * 128;

  f32x4 acc[8][4];
#pragma unroll
  for (int m = 0; m < 8; ++m)
#pragma unroll
    for (int n = 0; n < 4; ++n) acc[m][n] = (f32x4)0.f;

  const int ns1 = k1g >> 3, ns2 = k2g >> 3, ns = ns1 + ns2;
  const int lj = lane & 7, lr8 = lane >> 3;

  auto stage = [&](int buf, int s) {
    bool p2 = s >= ns1;
    const ushort_t* A = p2 ? A2 : A1;
    int Kg = p2 ? k2g : k1g;
    int sl = p2 ? (s - ns1) : s;
#pragma unroll
    for (int i = 0; i < 4; ++i) {
      int row = wv * 32 + i * 8 + lr8;
      int R = rowA0 + row;
      int lo = (wv * 32 + i * 8) * 64;
      if (SA) {
        size_t offA = ((size_t)R * (Kg * 2) + sl * 8 + lj) * 8;
        gload16(A + offA, &ldsA[buf][lo]);
        gload16(A + offA + (size_t)Kg * 8, &ldsA[buf][8192 + lo]);
      } else {
        // pre-swizzled source: LDS position lj of row R gets logical granule
        // G = lj^(R&7); slice-major storage: slice sl*2+((lj>>2)^((R>>2)&1)),
        // slot lj&3 (agg's q^(r&3) swizzle cancels the low bits).
        size_t offA = (size_t)(sl * 2 + ((lj >> 2) ^ ((R >> 2) & 1))) * SLICE_US +
                      (size_t)R * 32 + (size_t)((lj & 3) << 3);
        gload16(A + offA, &ldsA[buf][lo]);
      }
    }
  };

  stage(0, 0);
  __syncthreads();
  int cur = 0;

  for (int s = 0; s < ns; ++s) {
    bool p2 = s >= ns1;
    const ushort_t* Wf = p2 ? w2f : w1f;
    int sl = p2 ? (s - ns1) : s;
    int qcs = (p2 ? k2g : k1g) >> 2;

    // W fragment loads for this step: issued FIRST (oldest in vmcnt order),
    // so waiting on them does not drain the A-stage issued below.
    us8 bh[2][4], bl[2][4];
#pragma unroll
    for (int kc = 0; kc < 2; ++kc)
#pragma unroll
      for (int n = 0; n < 4; ++n) {
        size_t base = ((size_t)((wv * 4 + n) * qcs + sl * 2 + kc) * 2) * 512 + lane * 8;
        bh[kc][n] = *(const us8*)&Wf[base];
        bl[kc][n] = *(const us8*)&Wf[base + 512];
      }

    if (s + 1 < ns) stage(cur ^ 1, s + 1);  // stays in flight through compute

#pragma unroll
    for (int kc = 0; kc < 2; ++kc) {
      int kg = kc * 4 + kq;
      int swk = (kg ^ (fr & 7)) << 3;  // full 8-slot swizzle, conflict-free
#pragma unroll
      for (int mh = 0; mh < 2; ++mh) {
        us8 ah[4], al[4];
#pragma unroll
        for (int m = 0; m < 4; ++m) {
          int off = ((mh * 64 + m * 16 + fr) << 6) + swk;
          ah[m] = *(const us8*)&ldsA[cur][off];
          if (SA) al[m] = *(const us8*)&ldsA[cur][8192 + off];
        }
        // term-major: 16 independent MFMAs per term
#pragma unroll
        for (int m = 0; m < 4; ++m)
#pragma unroll
          for (int n = 0; n < 4; ++n)
            acc[mh * 4 + m][n] = mfma_bf16(ah[m], bh[kc][n], acc[mh * 4 + m][n]);
#pragma unroll
        for (int m = 0; m < 4; ++m)
#pragma unroll
          for (int n = 0; n < 4; ++n)
            acc[mh * 4 + m][n] = mfma_bf16(ah[m], bl[kc][n], acc[mh * 4 + m][n]);
        if (SA) {
#pragma unroll
          for (int m = 0; m < 4; ++m)
#pragma unroll
            for (int n = 0; n < 4; ++n)
              acc[mh * 4 + m][n] = mfma_bf16(al[m], bh[kc][n], acc[mh * 4 + m][n]);
        }
      }
    }
    __syncthreads();  // drains next-step stage (issued one compute-phase ago)
    cur ^= 1;
  }

  // ---- vectorized epilogue (C/D map: col=lane&15, row=(lane>>4)*4+reg) ----
  float bv4[4];
#pragma unroll
  for (int n = 0; n < 4; ++n) bv4[n] = bias[wv * 64 + n * 16 + fr];

  if (mode == 0) {
    ushort_t* eb = &ldsA[0][0] + wv * 2048;  // per-wave 4KB chunk region
#pragma unroll
    for (int c = 0; c < 4; ++c) {
      __syncthreads();  // region reuse across chunks
#pragma unroll
      for (int mm = 0; mm < 2; ++mm) {
#pragma unroll
        for (int n = 0; n < 4; ++n) {
          f32x4 v = acc[c * 2 + mm][n];
#pragma unroll
          for (int r = 0; r < 4; ++r)
            eb[(mm * 16 + kq * 4 + r) * 64 + n * 16 + fr] =
                f2bf(fmaxf(v[r] + bv4[n], 0.f));
        }
      }
      __syncthreads();  // ds writes visible before vector re-read
#pragma unroll
      for (int j = 0; j < 4; ++j) {
        int rl = j * 8 + (lane >> 3);
        int g8 = lane & 7;
        us8 v = *(const us8*)&eb[rl * 64 + g8 * 8];
        int R = bm * 128 + c * 32 + rl;
        int gi = wv * 8 + g8;
        if (R < N_NODES) {
          size_t addr = (size_t)(gi >> 2) * SLICE_US + (size_t)R * 32 +
                        (size_t)(((gi & 3) ^ (R & 3)) << 3);
          *(us8*)&oio[addr] = v;
        }
      }
    }
  } else {
    float* ebf = (float*)&ldsA[0][0] + wv * 2048;  // per-wave 8KB region
#pragma unroll
    for (int c = 0; c < 4; ++c) {
      __syncthreads();
#pragma unroll
      for (int mm = 0; mm < 2; ++mm) {
#pragma unroll
        for (int n = 0; n < 4; ++n) {
          f32x4 v = acc[c * 2 + mm][n];
#pragma unroll
          for (int r = 0; r < 4; ++r)
            ebf[(mm * 16 + kq * 4 + r) * 64 + n * 16 + fr] =
                fmaxf(v[r] + bv4[n], 0.f);
        }
      }
      __syncthreads();
#pragma unroll
      for (int j = 0; j < 8; ++j) {
        int rl = j * 4 + (lane >> 4);
        int seg = lane & 15;
        f32x4 v = *(const f32x4*)&ebf[rl * 64 + seg * 4];
        int R = bm * 128 + c * 32 + rl;
        if (R < N_NODES)
          *(f32x4*)&ofp[(size_t)R * HID + wv * 64 + seg * 4] = v;
      }
    }
  }
}

// ---------------- global mean pool (parallel over graph x chunk) ----------------

__global__ __launch_bounds__(256) void k_pool(const float* __restrict__ h,
                                              const int* __restrict__ gofs,
                                              float* __restrict__ pooled) {
  int g = blockIdx.y, c = blockIdx.x;  // 16 chunks
  int r0 = gofs[g], r1 = gofs[g + 1];
  int rg = threadIdx.x >> 6, lane = threadIdx.x & 63;
  float ax = 0.f, ay = 0.f, az = 0.f, aw = 0.f;
  for (int r = r0 + c * 4 + rg; r < r1; r += 64) {
    float4 v = *(const float4*)&h[(size_t)r * HID + lane * 4];
    ax += v.x; ay += v.y; az += v.z; aw += v.w;
  }
  __shared__ float4 sm[4][64];
  sm[rg][lane] = make_float4(ax, ay, az, aw);
  __syncthreads();
  if (rg == 0) {
    float4 s0 = sm[0][lane], s1 = sm[1][lane], s2 = sm[2][lane], s3 = sm[3][lane];
    float* p = &pooled[g * HID + lane * 4];
    atomicAdd(p + 0, s0.x + s1.x + s2.x + s3.x);
    atomicAdd(p + 1, s0.y + s1.y + s2.y + s3.y);
    atomicAdd(p + 2, s0.z + s1.z + s2.z + s3.z);
    atomicAdd(p + 3, s0.w + s1.w + s2.w + s3.w);
  }
}

// ---------------- head ----------------

__global__ __launch_bounds__(128) void k_head(const float* __restrict__ pooled,
                                              const int* __restrict__ gofs,
                                              const float* __restrict__ w1,
                                              const float* __restrict__ b1,
                                              const float* __restrict__ w2,
                                              const float* __restrict__ b2,
                                              float* __restrict__ out) {
  __shared__ float p[HID];
  __shared__ float g1[HID / 2];
  int g = blockIdx.x, t = threadIdx.x;
  float inv = 1.f / fmaxf((float)(gofs[g + 1] - gofs[g]), 1.f);
  p[t] = pooled[g * HID + t] * inv;
  p[t + 128] = pooled[g * HID + 128 + t] * inv;
  __syncthreads();
  float s = b1[t];
#pragma unroll 4
  for (int k = 0; k < HID; ++k) s = fmaf(p[k], w1[t * HID + k], s);
  g1[t] = fmaxf(s, 0.f);
  __syncthreads();
  if (t < N_OUT) {
    float s2 = b2[t];
#pragma unroll 4
    for (int k = 0; k < HID / 2; ++k) s2 = fmaf(g1[k], w2[t * (HID / 2) + k], s2);
    out[g * N_OUT + t] = s2;
  }
}

// ---------------- launch ----------------

extern "C" void kernel_launch(void* const* d_in, const int* in_sizes, int n_in,
                              void* d_out, int out_size, void* d_ws, size_t ws_size,
                              hipStream_t stream) {
  const float* x      = (const float*)d_in[0];
  const int*   ei     = (const int*)d_in[1];
  const int*   batch  = (const int*)d_in[2];
  const float* w1lw   = (const float*)d_in[3];
  const float* b1     = (const float*)d_in[4];
  const float* w1rw   = (const float*)d_in[5];
  const float* w2lw   = (const float*)d_in[6];
  const float* b2     = (const float*)d_in[7];
  const float* w2rw   = (const float*)d_in[8];
  const float* w3lw   = (const float*)d_in[9];
  const float* b3     = (const float*)d_in[10];
  const float* w3rw   = (const float*)d_in[11];
  const float* lin1_w = (const float*)d_in[12];
  const float* lin1_b = (const float*)d_in[13];
  const float* lin2_w = (const float*)d_in[14];
  const float* lin2_b = (const float*)d_in[15];
  float* out = (float*)d_out;

  const int* srcIdx = ei;
  const int* dstIdx = ei + N_EDGES;

  size_t off = 0;
  auto carve = [&](size_t bytes) {
    size_t r = off;
    off += (bytes + 255) & ~(size_t)255;
    return r;
  };
  char* ws = (char*)d_ws;
  int*      deg_priv = (int*)(ws + carve((size_t)8 * N_NODES * 4));
  int*      deg      = (int*)(ws + carve((size_t)N_NODES * 4));
  int*      rank     = (int*)(ws + carve((size_t)N_EDGES * 4));
  int*      rowptr   = (int*)(ws + carve((size_t)(N_NODES + 1) * 4));
  float*    deg_inv  = (float*)(ws + carve((size_t)N_NODES * 4));
  int*      esrc     = (int*)(ws + carve((size_t)N_EDGES * 4));
  int*      partial  = (int*)(ws + carve(64 * 4));
  int*      gofs     = (int*)(ws + carve((N_GRAPHS + 1) * 4));
  ushort_t* xio      = (ushort_t*)(ws + carve((size_t)M_PAD * 128 * 2));  // x split Kg=8
  ushort_t* agg1     = (ushort_t*)(ws + carve((size_t)M_PAD * 128 * 2));  // layer-1 agg split
  ushort_t* agg      = (ushort_t*)(ws + carve((size_t)M_PAD * 256 * 2));  // layers-2/3 agg, slice-major
  char*     h1blk    = ws + carve((size_t)M_PAD * HID * 4);  // h1 bf16-hi OR h3 fp32
  ushort_t* h1       = (ushort_t*)h1blk;
  float*    h3       = (float*)h1blk;  // alias: h1 dead before gemm3 writes
  ushort_t* h2       = (ushort_t*)(ws + carve((size_t)M_PAD * 256 * 2));
  ushort_t* wf1      = (ushort_t*)(ws + carve((size_t)2 * 32768 * 2));   // frag-major, Kg=8
  ushort_t* wf2      = (ushort_t*)(ws + carve((size_t)2 * 131072 * 2));  // frag-major, Kg=32
  ushort_t* wf3      = (ushort_t*)(ws + carve((size_t)2 * 131072 * 2));
  float*    pooled   = (float*)(ws + carve((size_t)N_GRAPHS * HID * 4));
  (void)ws_size; (void)n_in; (void)in_sizes; (void)out_size;

  hipMemsetAsync(deg_priv, 0, (size_t)8 * N_NODES * 4, stream);
  hipMemsetAsync(pooled, 0, (size_t)N_GRAPHS * HID * 4, stream);

  const int EB = (N_EDGES + 255) / 256;
  const int SB = (N_NODES + 1023) / 1024;

  k_hist<<<EB, 256, 0, stream>>>(dstIdx, deg_priv, rank);
  k_gofs<<<1, 256, 0, stream>>>(batch, gofs);
  k_scan1<<<SB, 1024, 0, stream>>>(deg_priv, deg, rowptr, partial);
  k_scan2<<<1, 64, 0, stream>>>(partial, rowptr);
  k_scan3<<<SB, 1024, 0, stream>>>(deg, partial, rowptr, deg_inv);
  k_place<<<EB, 256, 0, stream>>>(srcIdx, dstIdx, rowptr, deg_priv, rank, esrc);

  k_prep_x<<<(N_NODES * 8 + 255) / 256, 256, 0, stream>>>(x, xio);
  k_prep_w<<<dim3(32, 2, 3), 256, 0, stream>>>(w1lw, w1rw, w2lw, w2rw, w3lw, w3rw,
                                               wf1, wf2, wf3);

  const int GB = (N_NODES + 127) / 128;  // 391, 1-D grid (128-row, full-N tiles)
  const int AB = (N_NODES + 3) / 4;      // layer-1 agg grid
  const int AGB = 2048;                  // slice-pure agg grid (b&7 = slice -> XCD)

  // layer 1 (3-term split A)
  k_agg64s<<<AB, 256, 0, stream>>>(x, rowptr, esrc, deg_inv, agg1);
  k_gemm_mfma<1><<<GB, 256, 0, stream>>>(agg1, 8, wf1,
                                         xio, 8, wf1 + 32768,
                                         b1, h1, nullptr, 0);
  // layer 2 (A hi-only, 2-term)
  k_agg256s<<<AGB, 256, 0, stream>>>(h1, rowptr, esrc, deg_inv, agg);
  k_gemm_mfma<0><<<GB, 256, 0, stream>>>(agg, 32, wf2,
                                         h1, 32, wf2 + 131072,
                                         b2, h2, nullptr, 0);
  // layer 3 (fp32 out for pooling; h3 aliases dead h1)
  k_agg256s<<<AGB, 256, 0, stream>>>(h2, rowptr, esrc, deg_inv, agg);
  k_gemm_mfma<0><<<GB, 256, 0, stream>>>(agg, 32, wf3,
                                         h2, 32, wf3 + 131072,
                                         b3, nullptr, h3, 1);

  k_pool<<<dim3(16, N_GRAPHS), 256, 0, stream>>>(h3, gofs, pooled);
  k_head<<<N_GRAPHS, 128, 0, stream>>>(pooled, gofs, lin1_w, lin1_b, lin2_w, lin2_b, out);
}